// Round 3
// baseline (167.367 us; speedup 1.0000x reference)
//
#include <hip/hip_runtime.h>
#include <hip/hip_bf16.h>
#include <stdint.h>

#define MDIM 8192
#define KDIM 1024
#define NDIM 1024
#define NEXP 8
#define BM 256
#define BN 256
#define BK 64          // 16 K-tiles
#define LDSS 40        // fallback-kernel LDS stride

typedef __attribute__((ext_vector_type(8))) short bf16x8;
typedef __attribute__((ext_vector_type(4))) float floatx4;
typedef __attribute__((ext_vector_type(8))) unsigned short ushort8;

static __device__ __forceinline__ unsigned short f2b(float f) {
    unsigned int u = __float_as_uint(f);
    return (unsigned short)((u + 0x7fffu + ((u >> 16) & 1u)) >> 16);
}

// ---------------- pass 1: fp32 -> bf16 (a and b) into workspace ----------------
__global__ __launch_bounds__(256)
void cvt_bf16(const float* __restrict__ a, const float* __restrict__ b,
              unsigned short* __restrict__ wa, unsigned short* __restrict__ wb)
{
    const long t  = (long)blockIdx.x * 256 + threadIdx.x;
    const long NA = (long)MDIM * KDIM / 8;
    const float* src; unsigned short* dst; long v;
    if (t < NA) { src = a; dst = wa; v = t; }
    else        { src = b; dst = wb; v = t - NA; }
    const float4 lo = ((const float4*)src)[2 * v];
    const float4 hi = ((const float4*)src)[2 * v + 1];
    ushort8 o;
    o[0] = f2b(lo.x); o[1] = f2b(lo.y); o[2] = f2b(lo.z); o[3] = f2b(lo.w);
    o[4] = f2b(hi.x); o[5] = f2b(hi.y); o[6] = f2b(hi.z); o[7] = f2b(hi.w);
    ((ushort8*)dst)[v] = o;
}

// ---------------- pass 2: bf16 GEMM, 256x256x64, 8-phase counted-vmcnt ---------
#define GLDS(gp, lp) __builtin_amdgcn_global_load_lds(                        \
    (const __attribute__((address_space(1))) unsigned int*)(gp),              \
    (__attribute__((address_space(3))) unsigned int*)(lp), 16, 0, 0)

// A/B chain on the barrier variable (everything else identical):
//   v6: builtin s_barrier                      -> GEMM 42.6us, MfmaUtil 16.4
//   v7: asm s_barrier + sched_barrier(0)       -> GEMM 52.0us, MfmaUtil 13.8
//   v8 (this): asm s_barrier, NO sched_barrier -> tests the builtin-drain theory
// sched_barrier(0) was the m141 trap (order-pinning, -42% precedent); rule #18
// doesn't apply because frag ds_reads are compiler-emitted loads (compiler
// inserts its own dependency lgkmcnt before MFMA use).
#define BAR asm volatile("s_barrier" ::: "memory")

// LDS layout per buffer: [256 rows][64 bf16 = 8 chunks of 16B]; chunk position
// p holds global chunk p ^ (row & 7) (XOR swizzle, same involution on stage
// source and ds_read side -> conflict-free frag reads; bank-conflict PMC = 0).
//
// 8-phase schedule per iteration (tiles t=2*ii in buf0, t+1 in buf1), phase:
// {ds_read quad (+B in P1/P5); stage 1 half-tile (2 GLDS); s_barrier;
//  lgkmcnt(0); setprio(1); 16 MFMA; setprio(0); [vmcnt(4) at P4/P8]; s_barrier}
// Stage slots: P1/P2: A(t+1)->As1   P3/P4: B(t+2)->Bs0
//              P5/P6: A(t+2)->As0   P7/P8: B(t+3)->Bs1
// vmcnt(4) @P4: per-wave outstanding 12 = [B(t+1)x4, A(t+1)x4, B(t+2)x4];
// oldest 8 = buf1's tile -> wait leaves 4 in flight. @P8 symmetric for t+2.
// B indices wrap &15 in the last iteration; one vmcnt(0) drain after the loop.

__global__ __launch_bounds__(512, 2)
void grouped_gemm_v8(const unsigned short* __restrict__ A,   // [M,K] bf16
                     const unsigned short* __restrict__ B,   // [E,N,K] bf16
                     const int* __restrict__ seg_indptr,
                     const int* __restrict__ widx,
                     float* __restrict__ c)
{
    alignas(16) __shared__ unsigned short As0[BM * BK], As1[BM * BK];   // 32KB each
    alignas(16) __shared__ unsigned short Bs0[BN * BK], Bs1[BN * BK];   // 128KB total

    // bijective XCD swizzle (m204): nwg=156 -> q=19, r=4
    const int orig = (int)blockIdx.x;
    const int xcd = orig & 7, lin = orig >> 3;
    const int bid = (xcd < 4 ? xcd * 20 : 80 + (xcd - 4) * 19) + lin;

    const int NTN = NDIM / BN;  // 4
    int rem = bid;
    int s = -1, m0 = 0, seg_end = 0, n0 = 0;
    for (int i = 0; i < NEXP; ++i) {
        int ps = seg_indptr[i], pe = seg_indptr[i + 1];
        int nt = ((pe - ps + BM - 1) / BM) * NTN;
        if (rem < nt) { s = i; m0 = ps + (rem / NTN) * BM; n0 = (rem % NTN) * BN; seg_end = pe; break; }
        rem -= nt;
    }
    if (s < 0) return;

    const unsigned short* __restrict__ be = B + (size_t)widx[s] * (size_t)(NDIM * KDIM);

    const int tid  = (int)threadIdx.x;
    const int wave = tid >> 6;
    const int lane = tid & 63;

    // staging: 512 thr x 16B = 64 rows/call; thread -> row tid/8, pos tid&7,
    // global chunk (tid&7)^(row&7). 4 calls of 64 rows cover the 256-row tile.
    const int srow = tid >> 3;                       // 0..63
    const int gch  = ((tid & 7) ^ (srow & 7)) * 8;   // swizzled global chunk (elems)
    const unsigned short* ap[4];
    const unsigned short* bp[4];
#pragma unroll
    for (int j = 0; j < 4; ++j) {
        int ra = m0 + j * 64 + srow; if (ra >= MDIM) ra = MDIM - 1;  // clamp; masked at store
        ap[j] = A  + (size_t)ra * KDIM + gch;
        bp[j] = be + (size_t)(n0 + j * 64 + srow) * KDIM + gch;
    }
    const int ldso = wave * 512;   // elems; + j*4096; HW adds lane*16B

    const int wm = (wave >> 2) * 128;   // 2 wave-rows (M)
    const int wn = (wave & 3) * 64;     // 4 wave-cols (N)
    const int fr   = lane & 15;
    const int quad = lane >> 4;
    const int fro0 = ((0 * 4 + quad) ^ (fr & 7)) * 8;
    const int fro1 = ((1 * 4 + quad) ^ (fr & 7)) * 8;

    floatx4 acc[8][4] = {};
    bf16x8 b0[4], b1[4];   // B frags, read in P1/P5, reused P2-P4 / P6-P8

#define STAGE_A(DST, h, koff) do {                                            \
        GLDS(ap[2 * (h) + 0] + (koff), &DST[(2 * (h) + 0) * 4096 + ldso]);    \
        GLDS(ap[2 * (h) + 1] + (koff), &DST[(2 * (h) + 1) * 4096 + ldso]);    \
    } while (0)
#define STAGE_B(DST, h, koff) do {                                            \
        GLDS(bp[2 * (h) + 0] + (koff), &DST[(2 * (h) + 0) * 4096 + ldso]);    \
        GLDS(bp[2 * (h) + 1] + (koff), &DST[(2 * (h) + 1) * 4096 + ldso]);    \
    } while (0)

#define PHASE(AS, BS, Q, RB, STG, WV)                                         \
    do {                                                                      \
        bf16x8 af0  = *reinterpret_cast<const bf16x8*>(                       \
            &AS[(wm + (2 * (Q) + 0) * 16 + fr) * BK + fro0]);                 \
        bf16x8 af1  = *reinterpret_cast<const bf16x8*>(                       \
            &AS[(wm + (2 * (Q) + 1) * 16 + fr) * BK + fro0]);                 \
        bf16x8 af0b = *reinterpret_cast<const bf16x8*>(                       \
            &AS[(wm + (2 * (Q) + 0) * 16 + fr) * BK + fro1]);                 \
        bf16x8 af1b = *reinterpret_cast<const bf16x8*>(                       \
            &AS[(wm + (2 * (Q) + 1) * 16 + fr) * BK + fro1]);                 \
        if (RB) {                                                             \
            _Pragma("unroll")                                                 \
            for (int ni = 0; ni < 4; ++ni) {                                  \
                b0[ni] = *reinterpret_cast<const bf16x8*>(                    \
                    &BS[(wn + ni * 16 + fr) * BK + fro0]);                    \
                b1[ni] = *reinterpret_cast<const bf16x8*>(                    \
                    &BS[(wn + ni * 16 + fr) * BK + fro1]);                    \
            }                                                                 \
        }                                                                     \
        STG;                                                                  \
        if (RB) asm volatile("s_waitcnt lgkmcnt(8)" ::: "memory");            \
        BAR;                                                                  \
        asm volatile("s_waitcnt lgkmcnt(0)" ::: "memory");                    \
        __builtin_amdgcn_s_setprio(1);                                        \
        _Pragma("unroll")                                                     \
        for (int ni = 0; ni < 4; ++ni) {                                      \
            acc[2 * (Q) + 0][ni] = __builtin_amdgcn_mfma_f32_16x16x32_bf16(   \
                af0,  b0[ni], acc[2 * (Q) + 0][ni], 0, 0, 0);                 \
            acc[2 * (Q) + 1][ni] = __builtin_amdgcn_mfma_f32_16x16x32_bf16(   \
                af1,  b0[ni], acc[2 * (Q) + 1][ni], 0, 0, 0);                 \
            acc[2 * (Q) + 0][ni] = __builtin_amdgcn_mfma_f32_16x16x32_bf16(   \
                af0b, b1[ni], acc[2 * (Q) + 0][ni], 0, 0, 0);                 \
            acc[2 * (Q) + 1][ni] = __builtin_amdgcn_mfma_f32_16x16x32_bf16(   \
                af1b, b1[ni], acc[2 * (Q) + 1][ni], 0, 0, 0);                 \
        }                                                                     \
        __builtin_amdgcn_s_setprio(0);                                        \
        WV;                                                                   \
        BAR;                                                                  \
    } while (0)

#define VM4 asm volatile("s_waitcnt vmcnt(4)" ::: "memory")

    // prologue: tile0 -> buf0, B(1) -> Bs1 (A(1) staged in P1/P2 of iter 0)
    STAGE_A(As0, 0, 0); STAGE_A(As0, 1, 0);
    STAGE_B(Bs0, 0, 0); STAGE_B(Bs0, 1, 0);
    STAGE_B(Bs1, 0, BK); STAGE_B(Bs1, 1, BK);
    asm volatile("s_waitcnt vmcnt(4)" ::: "memory");   // A(0)+B(0) landed; B(1) in flight
    BAR;

#pragma unroll 1
    for (int ii = 0; ii < 8; ++ii) {
        const int t   = 2 * ii;
        const int kA1 = (t + 1) * BK;             // A(t+1), always <= 15*BK
        const int kN2 = ((t + 2) & 15) * BK;      // tile t+2 (wraps last iter)
        const int kN3 = ((t + 3) & 15) * BK;      // tile t+3 (wraps last iter)
        PHASE(As0, Bs0, 0, true,  STAGE_A(As1, 0, kA1), (void)0);
        PHASE(As0, Bs0, 1, false, STAGE_A(As1, 1, kA1), (void)0);
        PHASE(As0, Bs0, 2, false, STAGE_B(Bs0, 0, kN2), (void)0);
        PHASE(As0, Bs0, 3, false, STAGE_B(Bs0, 1, kN2), VM4);
        PHASE(As1, Bs1, 0, true,  STAGE_A(As0, 0, kN2), (void)0);
        PHASE(As1, Bs1, 1, false, STAGE_A(As0, 1, kN2), (void)0);
        PHASE(As1, Bs1, 2, false, STAGE_B(Bs1, 0, kN3), (void)0);
        PHASE(As1, Bs1, 3, false, STAGE_B(Bs1, 1, kN3), VM4);
    }
    asm volatile("s_waitcnt vmcnt(0)" ::: "memory");   // drain wrapped B prefetch

    // epilogue: C/D layout col=lane&15, row=quad*4+reg (m89-verified); mask rows
#pragma unroll
    for (int mi = 0; mi < 8; ++mi) {
        const int rbase = m0 + wm + mi * 16 + quad * 4;
#pragma unroll
        for (int ni = 0; ni < 4; ++ni) {
            const int col = n0 + wn + ni * 16 + fr;
#pragma unroll
            for (int j = 0; j < 4; ++j) {
                const int row = rbase + j;
                if (row < seg_end)
                    c[(size_t)row * NDIM + col] = acc[mi][ni][j];
            }
        }
    }
#undef STAGE_A
#undef STAGE_B
#undef PHASE
#undef VM4
}

// ---------------- fallback (R1 fused kernel) if workspace is too small ----------
__global__ __launch_bounds__(256, 2)
void grouped_gemm_fused(const float* __restrict__ a, const float* __restrict__ b,
                        const int* __restrict__ seg_indptr, const int* __restrict__ widx,
                        float* __restrict__ c)
{
    __shared__ unsigned short Asf[128 * LDSS];
    __shared__ unsigned short Bsf[128 * LDSS];
    const int NT = NDIM / 128;
    int rem = (int)blockIdx.x;
    int s = -1, m0 = 0, seg_end = 0, n0 = 0;
    for (int i = 0; i < NEXP; ++i) {
        int ps = seg_indptr[i], pe = seg_indptr[i + 1];
        int nt = ((pe - ps + 127) / 128) * NT;
        if (rem < nt) { s = i; m0 = ps + (rem / NT) * 128; n0 = (rem % NT) * 128; seg_end = pe; break; }
        rem -= nt;
    }
    if (s < 0) return;
    const float* __restrict__ be = b + (size_t)widx[s] * (size_t)(NDIM * KDIM);
    const int tid = (int)threadIdx.x;
    const int r0 = tid >> 3;
    const int kc = (tid & 7) * 4;
    int arow[4];
#pragma unroll
    for (int u = 0; u < 4; ++u) {
        int r = m0 + r0 + 32 * u;
        arow[u] = r < MDIM ? r : MDIM - 1;
    }
    const int lane = tid & 63;
    const int wave = tid >> 6;
    const int wm = (wave & 1) * 64;
    const int wn = (wave >> 1) * 64;
    const int fr = lane & 15;
    const int quad = lane >> 4;
    floatx4 acc[4][4] = {};
    float4 av[4], bv[4];
#pragma unroll
    for (int u = 0; u < 4; ++u) {
        av[u] = *reinterpret_cast<const float4*>(a + (size_t)arow[u] * KDIM + kc);
        bv[u] = *reinterpret_cast<const float4*>(be + (size_t)(n0 + r0 + 32 * u) * KDIM + kc);
    }
    for (int k0 = 0; k0 < KDIM; k0 += 32) {
        __syncthreads();
#pragma unroll
        for (int u = 0; u < 4; ++u) {
            ushort4 ua, ub;
            ua.x = f2b(av[u].x); ua.y = f2b(av[u].y); ua.z = f2b(av[u].z); ua.w = f2b(av[u].w);
            ub.x = f2b(bv[u].x); ub.y = f2b(bv[u].y); ub.z = f2b(bv[u].z); ub.w = f2b(bv[u].w);
            *reinterpret_cast<ushort4*>(&Asf[(r0 + 32 * u) * LDSS + kc]) = ua;
            *reinterpret_cast<ushort4*>(&Bsf[(r0 + 32 * u) * LDSS + kc]) = ub;
        }
        const int kn = (k0 + 32 < KDIM) ? (k0 + 32) : 0;
#pragma unroll
        for (int u = 0; u < 4; ++u) {
            av[u] = *reinterpret_cast<const float4*>(a + (size_t)arow[u] * KDIM + kn + kc);
            bv[u] = *reinterpret_cast<const float4*>(be + (size_t)(n0 + r0 + 32 * u) * KDIM + kn + kc);
        }
        __syncthreads();
        bf16x8 af[4], bf[4];
#pragma unroll
        for (int mi = 0; mi < 4; ++mi)
            af[mi] = *reinterpret_cast<const bf16x8*>(&Asf[(wm + mi * 16 + fr) * LDSS + quad * 8]);
#pragma unroll
        for (int ni = 0; ni < 4; ++ni)
            bf[ni] = *reinterpret_cast<const bf16x8*>(&Bsf[(wn + ni * 16 + fr) * LDSS + quad * 8]);
#pragma unroll
        for (int mi = 0; mi < 4; ++mi)
#pragma unroll
            for (int ni = 0; ni < 4; ++ni)
                acc[mi][ni] = __builtin_amdgcn_mfma_f32_16x16x32_bf16(af[mi], bf[ni], acc[mi][ni], 0, 0, 0);
    }
#pragma unroll
    for (int mi = 0; mi < 4; ++mi) {
        const int rbase = m0 + wm + mi * 16 + quad * 4;
#pragma unroll
        for (int ni = 0; ni < 4; ++ni) {
            const int col = n0 + wn + ni * 16 + fr;
#pragma unroll
            for (int j = 0; j < 4; ++j) {
                const int row = rbase + j;
                if (row < seg_end)
                    c[(size_t)row * NDIM + col] = acc[mi][ni][j];
            }
        }
    }
}

extern "C" void kernel_launch(void* const* d_in, const int* in_sizes, int n_in,
                              void* d_out, int out_size, void* d_ws, size_t ws_size,
                              hipStream_t stream) {
    const float* a          = (const float*)d_in[0];
    const float* b          = (const float*)d_in[1];
    const int*   seg_indptr = (const int*)d_in[5];
    const int*   widx       = (const int*)d_in[6];
    float*       out        = (float*)d_out;

    const size_t need = (size_t)(MDIM + NEXP * NDIM) * KDIM * sizeof(unsigned short); // 32 MiB
    if (ws_size >= need) {
        unsigned short* wa = (unsigned short*)d_ws;                       // [M,K] bf16
        unsigned short* wb = wa + (size_t)MDIM * KDIM;                    // [E,N,K] bf16
        hipLaunchKernelGGL(cvt_bf16, dim3(8192), dim3(256), 0, stream, a, b, wa, wb);
        // worst-case tiles: sum ceil(len/256) <= 32+7 = 39 m-tiles x 4 n-tiles = 156
        hipLaunchKernelGGL(grouped_gemm_v8, dim3(156), dim3(512), 0, stream,
                           wa, wb, seg_indptr, widx, out);
    } else {
        hipLaunchKernelGGL(grouped_gemm_fused, dim3(568), dim3(256), 0, stream,
                           a, b, seg_indptr, widx, out);
    }
}

// Round 4
// 164.704 us; speedup vs baseline: 1.0162x; 1.0162x over previous
//
#include <hip/hip_runtime.h>
#include <hip/hip_bf16.h>
#include <stdint.h>

#define MDIM 8192
#define KDIM 1024
#define NDIM 1024
#define NEXP 8
#define BM 256
#define BN 256
#define BK 64          // 16 K-tiles
#define LDSS 40        // fallback-kernel LDS stride

typedef __attribute__((ext_vector_type(8))) short bf16x8;
typedef __attribute__((ext_vector_type(4))) float floatx4;
typedef __attribute__((ext_vector_type(8))) unsigned short ushort8;

static __device__ __forceinline__ unsigned short f2b(float f) {
    unsigned int u = __float_as_uint(f);
    return (unsigned short)((u + 0x7fffu + ((u >> 16) & 1u)) >> 16);
}

// ---------------- pass 1: fp32 -> bf16 (a and b) into workspace ----------------
__global__ __launch_bounds__(256)
void cvt_bf16(const float* __restrict__ a, const float* __restrict__ b,
              unsigned short* __restrict__ wa, unsigned short* __restrict__ wb)
{
    const long t  = (long)blockIdx.x * 256 + threadIdx.x;
    const long NA = (long)MDIM * KDIM / 8;
    const float* src; unsigned short* dst; long v;
    if (t < NA) { src = a; dst = wa; v = t; }
    else        { src = b; dst = wb; v = t - NA; }
    const float4 lo = ((const float4*)src)[2 * v];
    const float4 hi = ((const float4*)src)[2 * v + 1];
    ushort8 o;
    o[0] = f2b(lo.x); o[1] = f2b(lo.y); o[2] = f2b(lo.z); o[3] = f2b(lo.w);
    o[4] = f2b(hi.x); o[5] = f2b(hi.y); o[6] = f2b(hi.z); o[7] = f2b(hi.w);
    ((ushort8*)dst)[v] = o;
}

// ---------------- pass 2: bf16 GEMM, 256x256x64, big-phase counted-vmcnt -------
#define GLDS(gp, lp) __builtin_amdgcn_global_load_lds(                        \
    (const __attribute__((address_space(1))) unsigned int*)(gp),              \
    (__attribute__((address_space(3))) unsigned int*)(lp), 16, 0, 0)

// v9 structure (R3 verdict: 8-phase lockstep serialized LDS-read bursts vs
// MFMA bursts at 1 block/CU; v6/v8 both ~41.5us = m248's 848TF plateau).
// One big compute phase per K-tile: 24 ds_read_b128 + 64 MFMA, scheduled by
// the compiler (m97 evidence: near-optimal fine lgkmcnt interleave). Only 2
// barriers per K-tile; counted vmcnt(8) keeps next tile's 8 GLDS in flight
// across the whole ~2500cyc compute phase (m97's one flaw -- the vmcnt(0)
// drain at __syncthreads -- removed via asm s_barrier + counted wait).
//
// Per K-tile t (buffers alternate t&1):
//   BAR                      // all waves' reads(t-1) done -> overwrite safe
//   STAGE(buf[(t+1)&1], t+1) // 8 GLDS issued, fly through compute
//   s_waitcnt vmcnt(8)       // stage(t) landed (outstanding = t & t+1 only)
//   BAR                      // all waves agree buf[t&1] complete
//   COMPUTE(buf[t&1])        // 8 B-frag + 16 A-frag ds_reads, 64 MFMA
// Last iteration stages a dummy (wrap &15); one vmcnt(0) drain after loop.
#define BAR asm volatile("s_barrier" ::: "memory")

// LDS layout per buffer: [256 rows][64 bf16 = 8 chunks of 16B]; chunk position
// p holds global chunk p ^ (row & 7) (XOR swizzle, same involution on stage
// source and ds_read side -> conflict-free frag reads; bank-conflict PMC = 0).

__global__ __launch_bounds__(512, 2)
void grouped_gemm_v9(const unsigned short* __restrict__ A,   // [M,K] bf16
                     const unsigned short* __restrict__ B,   // [E,N,K] bf16
                     const int* __restrict__ seg_indptr,
                     const int* __restrict__ widx,
                     float* __restrict__ c)
{
    alignas(16) __shared__ unsigned short As0[BM * BK], As1[BM * BK];   // 32KB each
    alignas(16) __shared__ unsigned short Bs0[BN * BK], Bs1[BN * BK];   // 128KB total

    // bijective XCD swizzle (m204): nwg=156 -> q=19, r=4
    const int orig = (int)blockIdx.x;
    const int xcd = orig & 7, lin = orig >> 3;
    const int bid = (xcd < 4 ? xcd * 20 : 80 + (xcd - 4) * 19) + lin;

    const int NTN = NDIM / BN;  // 4
    int rem = bid;
    int s = -1, m0 = 0, seg_end = 0, n0 = 0;
    for (int i = 0; i < NEXP; ++i) {
        int ps = seg_indptr[i], pe = seg_indptr[i + 1];
        int nt = ((pe - ps + BM - 1) / BM) * NTN;
        if (rem < nt) { s = i; m0 = ps + (rem / NTN) * BM; n0 = (rem % NTN) * BN; seg_end = pe; break; }
        rem -= nt;
    }
    if (s < 0) return;

    const unsigned short* __restrict__ be = B + (size_t)widx[s] * (size_t)(NDIM * KDIM);

    const int tid  = (int)threadIdx.x;
    const int wave = tid >> 6;
    const int lane = tid & 63;

    // staging: 512 thr x 16B = 64 rows/call; thread -> row tid/8, pos tid&7,
    // global chunk (tid&7)^(row&7). 4 calls of 64 rows cover the 256-row tile.
    const int srow = tid >> 3;                       // 0..63
    const int gch  = ((tid & 7) ^ (srow & 7)) * 8;   // swizzled global chunk (elems)
    const unsigned short* ap[4];
    const unsigned short* bp[4];
#pragma unroll
    for (int j = 0; j < 4; ++j) {
        int ra = m0 + j * 64 + srow; if (ra >= MDIM) ra = MDIM - 1;  // clamp; masked at store
        ap[j] = A  + (size_t)ra * KDIM + gch;
        bp[j] = be + (size_t)(n0 + j * 64 + srow) * KDIM + gch;
    }
    const int ldso = wave * 512;   // elems; + j*4096; HW adds lane*16B

    const int wm = (wave >> 2) * 128;   // 2 wave-rows (M)
    const int wn = (wave & 3) * 64;     // 4 wave-cols (N)
    const int fr   = lane & 15;
    const int quad = lane >> 4;
    const int fro0 = ((0 * 4 + quad) ^ (fr & 7)) * 8;
    const int fro1 = ((1 * 4 + quad) ^ (fr & 7)) * 8;

    floatx4 acc[8][4] = {};

#define STAGE(AD, BD, koff) do {                                              \
        _Pragma("unroll")                                                     \
        for (int j = 0; j < 4; ++j) {                                         \
            GLDS(ap[j] + (koff), &AD[j * 4096 + ldso]);                       \
            GLDS(bp[j] + (koff), &BD[j * 4096 + ldso]);                       \
        }                                                                     \
    } while (0)

// One K-tile: 8 B-frags up front (used by every MFMA), then per A-quad q:
// 4 A-frag reads + 16 MFMA. Compiler interleaves via dependency lgkmcnt --
// no manual lgkmcnt, no sched pins (m97-verified near-optimal behavior).
#define COMPUTE(AS, BS)                                                       \
    do {                                                                      \
        bf16x8 b0[4], b1[4];                                                  \
        _Pragma("unroll")                                                     \
        for (int ni = 0; ni < 4; ++ni) {                                      \
            b0[ni] = *reinterpret_cast<const bf16x8*>(                        \
                &BS[(wn + ni * 16 + fr) * BK + fro0]);                        \
            b1[ni] = *reinterpret_cast<const bf16x8*>(                        \
                &BS[(wn + ni * 16 + fr) * BK + fro1]);                        \
        }                                                                     \
        _Pragma("unroll")                                                     \
        for (int q = 0; q < 4; ++q) {                                         \
            bf16x8 af0  = *reinterpret_cast<const bf16x8*>(                   \
                &AS[(wm + (2 * q + 0) * 16 + fr) * BK + fro0]);               \
            bf16x8 af1  = *reinterpret_cast<const bf16x8*>(                   \
                &AS[(wm + (2 * q + 1) * 16 + fr) * BK + fro0]);               \
            bf16x8 af0b = *reinterpret_cast<const bf16x8*>(                   \
                &AS[(wm + (2 * q + 0) * 16 + fr) * BK + fro1]);               \
            bf16x8 af1b = *reinterpret_cast<const bf16x8*>(                   \
                &AS[(wm + (2 * q + 1) * 16 + fr) * BK + fro1]);               \
            _Pragma("unroll")                                                 \
            for (int ni = 0; ni < 4; ++ni) {                                  \
                acc[2 * q + 0][ni] = __builtin_amdgcn_mfma_f32_16x16x32_bf16( \
                    af0,  b0[ni], acc[2 * q + 0][ni], 0, 0, 0);               \
                acc[2 * q + 1][ni] = __builtin_amdgcn_mfma_f32_16x16x32_bf16( \
                    af1,  b0[ni], acc[2 * q + 1][ni], 0, 0, 0);               \
                acc[2 * q + 0][ni] = __builtin_amdgcn_mfma_f32_16x16x32_bf16( \
                    af0b, b1[ni], acc[2 * q + 0][ni], 0, 0, 0);               \
                acc[2 * q + 1][ni] = __builtin_amdgcn_mfma_f32_16x16x32_bf16( \
                    af1b, b1[ni], acc[2 * q + 1][ni], 0, 0, 0);               \
            }                                                                 \
        }                                                                     \
    } while (0)

#define VM8 asm volatile("s_waitcnt vmcnt(8)" ::: "memory")

    STAGE(As0, Bs0, 0);                       // prologue: tile 0 -> buf0

#pragma unroll 1
    for (int ii = 0; ii < 8; ++ii) {
        const int t = 2 * ii;
        // K-tile t (buf0)
        BAR;                                  // reads(t-1) done -> buf1 writable
        STAGE(As1, Bs1, (t + 1) * BK);        // t+1 <= 15, always real
        VM8;                                  // stage(t) landed
        BAR;                                  // all waves see buf0 complete
        COMPUTE(As0, Bs0);
        // K-tile t+1 (buf1)
        BAR;                                  // reads(t) done -> buf0 writable
        STAGE(As0, Bs0, ((t + 2) & 15) * BK); // wraps to dummy at last iter
        VM8;                                  // stage(t+1) landed
        BAR;
        COMPUTE(As1, Bs1);
    }
    asm volatile("s_waitcnt vmcnt(0)" ::: "memory");   // drain dummy stage

    // epilogue: C/D layout col=lane&15, row=quad*4+reg (m89-verified); mask rows
#pragma unroll
    for (int mi = 0; mi < 8; ++mi) {
        const int rbase = m0 + wm + mi * 16 + quad * 4;
#pragma unroll
        for (int ni = 0; ni < 4; ++ni) {
            const int col = n0 + wn + ni * 16 + fr;
#pragma unroll
            for (int j = 0; j < 4; ++j) {
                const int row = rbase + j;
                if (row < seg_end)
                    c[(size_t)row * NDIM + col] = acc[mi][ni][j];
            }
        }
    }
#undef STAGE
#undef COMPUTE
#undef VM8
}

// ---------------- fallback (R1 fused kernel) if workspace is too small ----------
__global__ __launch_bounds__(256, 2)
void grouped_gemm_fused(const float* __restrict__ a, const float* __restrict__ b,
                        const int* __restrict__ seg_indptr, const int* __restrict__ widx,
                        float* __restrict__ c)
{
    __shared__ unsigned short Asf[128 * LDSS];
    __shared__ unsigned short Bsf[128 * LDSS];
    const int NT = NDIM / 128;
    int rem = (int)blockIdx.x;
    int s = -1, m0 = 0, seg_end = 0, n0 = 0;
    for (int i = 0; i < NEXP; ++i) {
        int ps = seg_indptr[i], pe = seg_indptr[i + 1];
        int nt = ((pe - ps + 127) / 128) * NT;
        if (rem < nt) { s = i; m0 = ps + (rem / NT) * 128; n0 = (rem % NT) * 128; seg_end = pe; break; }
        rem -= nt;
    }
    if (s < 0) return;
    const float* __restrict__ be = b + (size_t)widx[s] * (size_t)(NDIM * KDIM);
    const int tid = (int)threadIdx.x;
    const int r0 = tid >> 3;
    const int kc = (tid & 7) * 4;
    int arow[4];
#pragma unroll
    for (int u = 0; u < 4; ++u) {
        int r = m0 + r0 + 32 * u;
        arow[u] = r < MDIM ? r : MDIM - 1;
    }
    const int lane = tid & 63;
    const int wave = tid >> 6;
    const int wm = (wave & 1) * 64;
    const int wn = (wave >> 1) * 64;
    const int fr = lane & 15;
    const int quad = lane >> 4;
    floatx4 acc[4][4] = {};
    float4 av[4], bv[4];
#pragma unroll
    for (int u = 0; u < 4; ++u) {
        av[u] = *reinterpret_cast<const float4*>(a + (size_t)arow[u] * KDIM + kc);
        bv[u] = *reinterpret_cast<const float4*>(be + (size_t)(n0 + r0 + 32 * u) * KDIM + kc);
    }
    for (int k0 = 0; k0 < KDIM; k0 += 32) {
        __syncthreads();
#pragma unroll
        for (int u = 0; u < 4; ++u) {
            ushort4 ua, ub;
            ua.x = f2b(av[u].x); ua.y = f2b(av[u].y); ua.z = f2b(av[u].z); ua.w = f2b(av[u].w);
            ub.x = f2b(bv[u].x); ub.y = f2b(bv[u].y); ub.z = f2b(bv[u].z); ub.w = f2b(bv[u].w);
            *reinterpret_cast<ushort4*>(&Asf[(r0 + 32 * u) * LDSS + kc]) = ua;
            *reinterpret_cast<ushort4*>(&Bsf[(r0 + 32 * u) * LDSS + kc]) = ub;
        }
        const int kn = (k0 + 32 < KDIM) ? (k0 + 32) : 0;
#pragma unroll
        for (int u = 0; u < 4; ++u) {
            av[u] = *reinterpret_cast<const float4*>(a + (size_t)arow[u] * KDIM + kn + kc);
            bv[u] = *reinterpret_cast<const float4*>(be + (size_t)(n0 + r0 + 32 * u) * KDIM + kn + kc);
        }
        __syncthreads();
        bf16x8 af[4], bf[4];
#pragma unroll
        for (int mi = 0; mi < 4; ++mi)
            af[mi] = *reinterpret_cast<const bf16x8*>(&Asf[(wm + mi * 16 + fr) * LDSS + quad * 8]);
#pragma unroll
        for (int ni = 0; ni < 4; ++ni)
            bf[ni] = *reinterpret_cast<const bf16x8*>(&Bsf[(wn + ni * 16 + fr) * LDSS + quad * 8]);
#pragma unroll
        for (int mi = 0; mi < 4; ++mi)
#pragma unroll
            for (int ni = 0; ni < 4; ++ni)
                acc[mi][ni] = __builtin_amdgcn_mfma_f32_16x16x32_bf16(af[mi], bf[ni], acc[mi][ni], 0, 0, 0);
    }
#pragma unroll
    for (int mi = 0; mi < 4; ++mi) {
        const int rbase = m0 + wm + mi * 16 + quad * 4;
#pragma unroll
        for (int ni = 0; ni < 4; ++ni) {
            const int col = n0 + wn + ni * 16 + fr;
#pragma unroll
            for (int j = 0; j < 4; ++j) {
                const int row = rbase + j;
                if (row < seg_end)
                    c[(size_t)row * NDIM + col] = acc[mi][ni][j];
            }
        }
    }
}

extern "C" void kernel_launch(void* const* d_in, const int* in_sizes, int n_in,
                              void* d_out, int out_size, void* d_ws, size_t ws_size,
                              hipStream_t stream) {
    const float* a          = (const float*)d_in[0];
    const float* b          = (const float*)d_in[1];
    const int*   seg_indptr = (const int*)d_in[5];
    const int*   widx       = (const int*)d_in[6];
    float*       out        = (float*)d_out;

    const size_t need = (size_t)(MDIM + NEXP * NDIM) * KDIM * sizeof(unsigned short); // 32 MiB
    if (ws_size >= need) {
        unsigned short* wa = (unsigned short*)d_ws;                       // [M,K] bf16
        unsigned short* wb = wa + (size_t)MDIM * KDIM;                    // [E,N,K] bf16
        hipLaunchKernelGGL(cvt_bf16, dim3(8192), dim3(256), 0, stream, a, b, wa, wb);
        // worst-case tiles: sum ceil(len/256) <= 32+7 = 39 m-tiles x 4 n-tiles = 156
        hipLaunchKernelGGL(grouped_gemm_v9, dim3(156), dim3(512), 0, stream,
                           wa, wb, seg_indptr, widx, out);
    } else {
        hipLaunchKernelGGL(grouped_gemm_fused, dim3(568), dim3(256), 0, stream,
                           a, b, seg_indptr, widx, out);
    }
}